// Round 1
// baseline (268.651 us; speedup 1.0000x reference)
//
#include <hip/hip_runtime.h>

#define IN_CH  128
#define OUTW   64
#define ROWS_PB 256
#define KT     32

// ---------------- flag kernel: mark nodes with in-degree > 0 ----------------
__global__ __launch_bounds__(256) void flag_edges(const int* __restrict__ col,
                                                  unsigned* __restrict__ flag,
                                                  int E, int N) {
    int e = blockIdx.x * blockDim.x + threadIdx.x;
    if (e < E) {
        int c = col[e];
        if ((unsigned)c < (unsigned)N) atomicOr(&flag[c], 1u);
    }
}

// ---------------- masked GEMM: out = (x @ W) * (flag>0) ----------------
// 256 threads, 256 rows x 64 cols per block, 8x8 micro-tile per thread.
__global__ __launch_bounds__(256) void gemm_mask(const float* __restrict__ x,
                                                 const float* __restrict__ W,
                                                 const unsigned* __restrict__ flag,
                                                 float* __restrict__ out, int N) {
    __shared__ float xs[ROWS_PB][KT + 1];   // +1 pad: kills bank conflicts on xs[r][k]
    __shared__ float Wls[KT][OUTW];

    const int tid = threadIdx.x;
    const int tx  = tid & 7;      // 8 column-threads
    const int ty  = tid >> 3;     // 32 row-threads
    const int c0  = tx * 8;
    const int r0  = ty * 8;
    const int rowBase = blockIdx.x * ROWS_PB;

    float acc[8][8];
    #pragma unroll
    for (int i = 0; i < 8; ++i)
        #pragma unroll
        for (int j = 0; j < 8; ++j) acc[i][j] = 0.f;

    for (int k0 = 0; k0 < IN_CH; k0 += KT) {
        // stage x tile: ROWS_PB x KT floats (8 float4 per thread)
        #pragma unroll
        for (int p = 0; p < (ROWS_PB * KT) / (256 * 4); ++p) {
            int idx = p * 256 + tid;           // float4 index
            int rl  = idx >> 3;                // KT/4 = 8 float4 per row
            int kk  = (idx & 7) * 4;
            int row = rowBase + rl;
            float4 v = make_float4(0.f, 0.f, 0.f, 0.f);
            if (row < N) v = *(const float4*)(x + (size_t)row * IN_CH + k0 + kk);
            xs[rl][kk + 0] = v.x; xs[rl][kk + 1] = v.y;
            xs[rl][kk + 2] = v.z; xs[rl][kk + 3] = v.w;
        }
        // stage W tile: KT x 64 floats (2 float4 per thread)
        #pragma unroll
        for (int p = 0; p < (KT * OUTW) / (256 * 4); ++p) {
            int idx = p * 256 + tid;
            int kk  = idx >> 4;
            int cc  = (idx & 15) * 4;
            float4 v = *(const float4*)(W + (size_t)(k0 + kk) * OUTW + cc);
            *(float4*)&Wls[kk][cc] = v;
        }
        __syncthreads();

        #pragma unroll
        for (int k = 0; k < KT; ++k) {
            float a[8];
            #pragma unroll
            for (int i = 0; i < 8; ++i) a[i] = xs[r0 + i][k];
            float4 b0 = *(const float4*)&Wls[k][c0];
            float4 b1 = *(const float4*)&Wls[k][c0 + 4];
            float b[8] = {b0.x, b0.y, b0.z, b0.w, b1.x, b1.y, b1.z, b1.w};
            #pragma unroll
            for (int i = 0; i < 8; ++i)
                #pragma unroll
                for (int j = 0; j < 8; ++j)
                    acc[i][j] = fmaf(a[i], b[j], acc[i][j]);
        }
        __syncthreads();
    }

    // epilogue: mask by in-degree flag, write 8 rows x 8 cols
    #pragma unroll
    for (int i = 0; i < 8; ++i) {
        int row = rowBase + r0 + i;
        if (row < N) {
            float m = flag[row] ? 1.f : 0.f;
            float4 v0 = make_float4(acc[i][0] * m, acc[i][1] * m,
                                    acc[i][2] * m, acc[i][3] * m);
            float4 v1 = make_float4(acc[i][4] * m, acc[i][5] * m,
                                    acc[i][6] * m, acc[i][7] * m);
            *(float4*)(out + (size_t)row * OUTW + c0)     = v0;
            *(float4*)(out + (size_t)row * OUTW + c0 + 4) = v1;
        }
    }
}

extern "C" void kernel_launch(void* const* d_in, const int* in_sizes, int n_in,
                              void* d_out, int out_size, void* d_ws, size_t ws_size,
                              hipStream_t stream) {
    const float* x  = (const float*)d_in[0];
    const int*   ei = (const int*)d_in[1];   // harness stores integer inputs as int32
    const float* W  = (const float*)d_in[3];
    float* out = (float*)d_out;

    const int N = in_sizes[0] / IN_CH;       // 100000
    const int E = in_sizes[1] / 2;           // 1600000
    const int* col = ei + E;                 // edge_index[1]

    unsigned* flag = (unsigned*)d_ws;        // N * 4 bytes of scratch

    hipMemsetAsync(flag, 0, (size_t)N * sizeof(unsigned), stream);
    flag_edges<<<(E + 255) / 256, 256, 0, stream>>>(col, flag, E, N);

    int blocks = (N + ROWS_PB - 1) / ROWS_PB;
    gemm_mask<<<blocks, 256, 0, stream>>>(x, W, flag, out, N);
}

// Round 2
// 229.932 us; speedup vs baseline: 1.1684x; 1.1684x over previous
//
#include <hip/hip_runtime.h>

#define IN_CH 128
#define OUTW  64
#define KT    32
#define RPB   128                 // rows per gemm block
#define XS_STRIDE (KT + 4)        // 36 words; 36%32==4 -> even bank spread for b128
#define NPARTS 256
#define WORDS_MAX 3200            // supports N <= 102400 in LDS bitmap

// ---- phase 1a: per-block LDS bitmap of nodes with in-degree>0 (no global atomics)
__global__ __launch_bounds__(256) void flag_parts(const int* __restrict__ col,
                                                  unsigned* __restrict__ parts,
                                                  int E, int N, int chunkE) {
    __shared__ unsigned bm[WORDS_MAX];
    const int tid = threadIdx.x;
    const int words = (N + 31) >> 5;
    for (int w = tid; w < words; w += 256) bm[w] = 0u;
    __syncthreads();
    const int e0 = blockIdx.x * chunkE;
    const int e1 = min(E, e0 + chunkE);
    for (int e = e0 + tid; e < e1; e += 256) {
        int c = col[e];
        if ((unsigned)c < (unsigned)N) atomicOr(&bm[c >> 5], 1u << (c & 31));
    }
    __syncthreads();
    unsigned* dst = parts + (size_t)blockIdx.x * words;
    for (int w = tid; w < words; w += 256) dst[w] = bm[w];
}

// ---- phase 1b fallback (small ws): global atomic bitmap (12.5 KB footprint)
__global__ __launch_bounds__(256) void flag_atomic(const int* __restrict__ col,
                                                   unsigned* __restrict__ bm,
                                                   int E, int N) {
    int e = blockIdx.x * blockDim.x + threadIdx.x;
    if (e < E) {
        int c = col[e];
        if ((unsigned)c < (unsigned)N) atomicOr(&bm[c >> 5], 1u << (c & 31));
    }
}

// ---- phase 2: out = (x @ W) masked by in-degree>0
// 256 threads = 128 rows x 2 column-halves; thread = 1 row x 32 cols, acc[32].
// W row (32 floats) is wave-uniform -> scalar loads, ~0 LDS traffic for B.
__global__ __launch_bounds__(256) void gemm_mask(const float* __restrict__ x,
                                                 const float* __restrict__ W,
                                                 const unsigned* __restrict__ parts,
                                                 int nParts,
                                                 float* __restrict__ out, int N) {
    __shared__ float xs[RPB * XS_STRIDE];
    __shared__ unsigned mw[RPB / 32];

    const int tid = threadIdx.x;
    const int r   = tid & (RPB - 1);
    const int half = __builtin_amdgcn_readfirstlane(tid >> 7);  // wave-uniform 0/1
    const int rowBase = blockIdx.x * RPB;
    const int row = rowBase + r;

    float acc[32];
    #pragma unroll
    for (int i = 0; i < 32; ++i) acc[i] = 0.f;

    for (int k0 = 0; k0 < IN_CH; k0 += KT) {
        // stage 128 rows x 32 k (16 KB), coalesced: a wave covers 1 KB contiguous
        #pragma unroll
        for (int p = 0; p < (RPB * KT) / (256 * 4); ++p) {   // 4 float4 per thread
            int idx = p * 256 + tid;
            int rl = idx >> 3;            // 8 float4 per row
            int kk = (idx & 7) * 4;
            float4 v = make_float4(0.f, 0.f, 0.f, 0.f);
            int gr = rowBase + rl;
            if (gr < N) v = *(const float4*)(x + (size_t)gr * IN_CH + k0 + kk);
            *(float4*)&xs[rl * XS_STRIDE + kk] = v;
        }
        __syncthreads();

        #pragma unroll
        for (int k4 = 0; k4 < KT; k4 += 4) {
            float4 a4 = *(const float4*)&xs[r * XS_STRIDE + k4];
            #pragma unroll
            for (int j = 0; j < 4; ++j) {
                const int k = k0 + k4 + j;
                const float4* wr = (const float4*)(W + (size_t)k * OUTW + half * 32);
                const float a = (j == 0) ? a4.x : (j == 1) ? a4.y : (j == 2) ? a4.z : a4.w;
                #pragma unroll
                for (int q = 0; q < 8; ++q) {
                    float4 b = wr[q];                 // uniform -> s_load
                    acc[q * 4 + 0] = fmaf(a, b.x, acc[q * 4 + 0]);
                    acc[q * 4 + 1] = fmaf(a, b.y, acc[q * 4 + 1]);
                    acc[q * 4 + 2] = fmaf(a, b.z, acc[q * 4 + 2]);
                    acc[q * 4 + 3] = fmaf(a, b.w, acc[q * 4 + 3]);
                }
            }
        }
        __syncthreads();
    }

    // merge the in-degree bitmap parts for this block's 4 words
    const int wordsTotal = (N + 31) >> 5;
    if (tid < RPB / 32) mw[tid] = 0u;
    __syncthreads();
    {
        int w = tid >> 6;                  // 0..3
        int gw = (rowBase >> 5) + w;
        unsigned part = 0u;
        if (gw < wordsTotal)
            for (int g = tid & 63; g < nParts; g += 64)
                part |= parts[(size_t)g * wordsTotal + gw];
        atomicOr(&mw[w], part);
    }
    __syncthreads();

    if (row < N) {
        float m = ((mw[r >> 5] >> (r & 31)) & 1u) ? 1.f : 0.f;
        float* op = out + (size_t)row * OUTW + half * 32;
        #pragma unroll
        for (int q = 0; q < 8; ++q) {
            float4 v = make_float4(acc[q * 4 + 0] * m, acc[q * 4 + 1] * m,
                                   acc[q * 4 + 2] * m, acc[q * 4 + 3] * m);
            *(float4*)(op + q * 4) = v;
        }
    }
}

extern "C" void kernel_launch(void* const* d_in, const int* in_sizes, int n_in,
                              void* d_out, int out_size, void* d_ws, size_t ws_size,
                              hipStream_t stream) {
    const float* x  = (const float*)d_in[0];
    const int*   ei = (const int*)d_in[1];
    const float* W  = (const float*)d_in[3];
    float* out = (float*)d_out;

    const int N = in_sizes[0] / IN_CH;     // 100000
    const int E = in_sizes[1] / 2;         // 1600000
    const int* col = ei + E;               // edge_index[1]

    const int words = (N + 31) >> 5;
    unsigned* ws = (unsigned*)d_ws;
    const size_t need = (size_t)NPARTS * words * sizeof(unsigned);

    int gemmBlocks = (N + RPB - 1) / RPB;

    if (ws_size >= need && words <= WORDS_MAX) {
        int chunkE = (E + NPARTS - 1) / NPARTS;
        flag_parts<<<NPARTS, 256, 0, stream>>>(col, ws, E, N, chunkE);
        gemm_mask<<<gemmBlocks, 256, 0, stream>>>(x, W, ws, NPARTS, out, N);
    } else {
        hipMemsetAsync(ws, 0, (size_t)words * sizeof(unsigned), stream);
        flag_atomic<<<(E + 255) / 256, 256, 0, stream>>>(col, ws, E, N);
        gemm_mask<<<gemmBlocks, 256, 0, stream>>>(x, W, ws, 1, out, N);
    }
}